// Round 2
// baseline (9595.436 us; speedup 1.0000x reference)
//
#include <hip/hip_runtime.h>
#include <hip/hip_bf16.h>

// EmbedAlign: emb gather -> 3-layer BiLSTM (seq scan) -> mu/sigma nets ->
// reparam z -> KL + negative-sampling scores + alignment marginal -> scalar.
// All fp32. D=512, L=1024, NNEG=8192, V=32000.

// ---------------------------------------------------------------------------
// Generic fp32 NT GEMM: C[M,N] = A[M,K] . B[N,K]^T (+bias) with epilogues.
// GATHER: B row n comes from B[idx[n]].  EPI: 0=store(+bias,+relu),
// 1=atomicAdd rowsum(exp(C)) into C-vector, 2=atomicAdd sum(exp/(exp+negf)).
// Tiles 64x64, BK=16, 256 threads, 4x4 per thread.
// ---------------------------------------------------------------------------
template<bool GATHER, bool RELU, int EPI>
__global__ __launch_bounds__(256) void gemm_nt(
    const float* __restrict__ A, const float* __restrict__ B,
    const float* __restrict__ bias, const int* __restrict__ idx,
    float* __restrict__ C, const float* __restrict__ negf,
    float* __restrict__ outsum, int M, int N, int K)
{
    __shared__ float As[16][68];
    __shared__ float Bs[16][68];
    __shared__ float wsum[4];

    const int tid = threadIdx.x;
    const int bm = blockIdx.x, bn = blockIdx.y;
    const int tx = tid & 15, ty = tid >> 4;
    const int lr = tid >> 2;          // 0..63: tile row being loaded
    const int lk = (tid & 3) * 4;     // 0,4,8,12: k sub-offset

    const long arow = (long)bm * 64 + lr;
    const int  brow = bn * 64 + lr;
    const long bsrc = GATHER ? (long)idx[brow] : (long)brow;
    const float* Ap = A + arow * K + lk;
    const float* Bp = B + bsrc * K + lk;

    float acc[4][4] = {};

    for (int k0 = 0; k0 < K; k0 += 16) {
        float4 av = *(const float4*)(Ap + k0);
        float4 bv = *(const float4*)(Bp + k0);
        __syncthreads();
        As[lk + 0][lr] = av.x; As[lk + 1][lr] = av.y;
        As[lk + 2][lr] = av.z; As[lk + 3][lr] = av.w;
        Bs[lk + 0][lr] = bv.x; Bs[lk + 1][lr] = bv.y;
        Bs[lk + 2][lr] = bv.z; Bs[lk + 3][lr] = bv.w;
        __syncthreads();
#pragma unroll
        for (int k = 0; k < 16; ++k) {
            float4 a = *(const float4*)&As[k][ty * 4];
            float4 b = *(const float4*)&Bs[k][tx * 4];
            float ar[4] = {a.x, a.y, a.z, a.w};
            float br[4] = {b.x, b.y, b.z, b.w};
#pragma unroll
            for (int i = 0; i < 4; ++i)
#pragma unroll
                for (int j = 0; j < 4; ++j)
                    acc[i][j] += ar[i] * br[j];
        }
    }

    const int row0 = bm * 64 + ty * 4, col0 = bn * 64 + tx * 4;

    if (EPI == 0) {
#pragma unroll
        for (int i = 0; i < 4; ++i) {
            float4 v;
            float vv[4];
#pragma unroll
            for (int j = 0; j < 4; ++j) {
                float x = acc[i][j];
                if (bias) x += bias[col0 + j];
                if (RELU) x = x > 0.f ? x : 0.f;
                vv[j] = x;
            }
            v.x = vv[0]; v.y = vv[1]; v.z = vv[2]; v.w = vv[3];
            *(float4*)&C[(long)(row0 + i) * N + col0] = v;
        }
    } else if (EPI == 1) {
        // per-row sum of exp over this tile's 64 cols -> atomicAdd C[row]
#pragma unroll
        for (int i = 0; i < 4; ++i) {
            float s = expf(acc[i][0]) + expf(acc[i][1]) +
                      expf(acc[i][2]) + expf(acc[i][3]);
            s += __shfl_xor(s, 1); s += __shfl_xor(s, 2);
            s += __shfl_xor(s, 4); s += __shfl_xor(s, 8);
            if (tx == 0) atomicAdd(&C[row0 + i], s);
        }
    } else {
        float t = 0.f;
#pragma unroll
        for (int i = 0; i < 4; ++i) {
            float nf = negf[row0 + i];
#pragma unroll
            for (int j = 0; j < 4; ++j) {
                float e = expf(acc[i][j]);
                t += e / (e + nf);
            }
        }
#pragma unroll
        for (int o = 1; o < 64; o <<= 1) t += __shfl_xor(t, o);
        if ((tid & 63) == 0) wsum[tid >> 6] = t;
        __syncthreads();
        if (tid == 0) atomicAdd(outsum, wsum[0] + wsum[1] + wsum[2] + wsum[3]);
    }
}

// ---------------------------------------------------------------------------
// BiLSTM scan, 1024 steps. Grid = 256 WGs x 256 threads: blocks 0..127
// forward, 128..255 backward (1 WG/CU).
//
// R3 restructure: wave-per-h. Wave v (tid>>6) owns h index j = w*4+v and
// computes ALL FOUR of its gates in-wave: lane -> (gate = lane>>4,
// chunk c = lane&15, 32 cols). After the 16-lane butterfly reduce the four
// gate sums sit at lanes {0,16,32,48}; lane 0 gathers them with __shfl and
// every lane runs the LSTM cell redundantly (c-state replicated in regs).
// This removes the ga[] LDS round-trip, the SECOND __syncthreads, and the
// cross-wave handoff to wave 0 (which previously serialized the cell behind
// the slowest sibling wave) -- ~400-600 cy off the global per-step chain.
//
// The one remaining barrier (h staging) is made overwrite-safe by double-
// buffering hs[] by step parity: a wave can only reach the hs[p] writes of
// step s+2 after passing the barrier of step s+1, which proves every wave
// finished its reads of hs[p] at step s.
//
// Whh chunk (16 gate rows x 512) staged ONCE into LDS, per-thread-contiguous
// stride-36 layout (consecutive lanes cover all 32 banks per b128 -- the
// measured conflict-free pattern). Register-resident weights were demoted by
// the allocator two sessions running (VGPR 84 -> 52, per-step global
// reloads); LDS cannot be demoted. hs chunks also stride-36.
//
// Cross-WG step exchange unchanged: one 8-byte relaxed agent-scope atomic
// per h (low 32 = fp32 h, high 32 = tag s+1); buffers alternate by parity;
// tag s+1 on all slots implies every WG consumed h_{s-1}.
// ---------------------------------------------------------------------------
__global__ __launch_bounds__(256, 1) void lstm_scan(
    const float* __restrict__ Xf, const float* __restrict__ Xb, // (1024,2048) pre-proj incl bias
    const float* __restrict__ Whh,                              // (2,2048,512)
    float* __restrict__ out,                                    // (1024,1024) [hf|hb]
    unsigned long long* __restrict__ hbuf)                      // (2 dirs,2 bufs,512 slots), zeroed
{
    const int tid  = threadIdx.x;
    const int dir  = blockIdx.x >> 7;
    const int w    = blockIdx.x & 127;
    const int lane = tid & 63;
    const int v    = tid >> 6;        // wave 0..3: owns h index j = w*4+v
    const int gate = lane >> 4;       // 0..3 within wave
    const int c    = lane & 15;       // col chunk 0..15 (32 cols each)
    const int j    = w * 4 + v;       // h index 0..511
    const int grow = gate * 512 + j;  // row in (2048 x 512) Whh

    __shared__ float Wl[256 * 36];    // per-thread 32 w + 4 pad
    __shared__ float hs[2][16 * 36];  // parity-double-buffered h staging

    // ---- stage this thread's Whh row-chunk into LDS (once) ----
    {
        const float4* Wrow = (const float4*)(Whh + ((long)dir * 2048 + grow) * 512 + c * 32);
        float4* wl4s = (float4*)Wl + tid * 9;
#pragma unroll
        for (int q = 0; q < 8; ++q) wl4s[q] = Wrow[q];
    }
    __syncthreads();

    const float* Xp = dir ? Xb : Xf;
    unsigned long long* myh = hbuf + dir * 1024;

    float cst = 0.f;                  // LSTM c-state, replicated across lanes
    bool dead = false;

    const float4* wl4 = (const float4*)Wl + tid * 9;

    for (int s = 0; s < 1024; ++s) {
        const int t = dir ? (1023 - s) : s;
        // prefetch this wave's gate-x for its h (same addr for a 16-lane
        // group -> broadcast); issued before the poll, off critical path
        float xg = Xp[(long)t * 2048 + grow];

        // ---- poll h_{s-1} slots (tag==s) ----
        unsigned long long* rb = myh + ((s + 1) & 1) * 512;
        unsigned long long v0, v1;
        unsigned it = 0;
        for (;;) {
            v0 = __hip_atomic_load(&rb[tid],       __ATOMIC_RELAXED, __HIP_MEMORY_SCOPE_AGENT);
            v1 = __hip_atomic_load(&rb[tid + 256], __ATOMIC_RELAXED, __HIP_MEMORY_SCOPE_AGENT);
            if (dead || ((int)(v0 >> 32) == s && (int)(v1 >> 32) == s)) break;
            if (++it > (1u << 20)) { dead = true; break; }   // anti-hang
        }
        // stage into padded chunks: slot i -> hs[p][(i>>5)*36 + (i&31)]
        float* hsb = hs[s & 1];
        hsb[(tid >> 5) * 36 + (tid & 31)]               = __uint_as_float((unsigned)v0);
        hsb[((tid + 256) >> 5) * 36 + (tid & 31)]       = __uint_as_float((unsigned)v1);
        __syncthreads();   // the ONLY barrier per step

        // ---- 32-wide partial dot (8 float4 pairs), conflict-free LDS ----
        const float4* hs4 = (const float4*)hsb + c * 9;
        float a0 = 0.f, a1 = 0.f;
#pragma unroll
        for (int q = 0; q < 8; q += 2) {
            float4 w0 = wl4[q],     h0 = hs4[q];
            float4 w1 = wl4[q + 1], h1 = hs4[q + 1];
            a0 += w0.x*h0.x + w0.y*h0.y + w0.z*h0.z + w0.w*h0.w;
            a1 += w1.x*h1.x + w1.y*h1.y + w1.z*h1.z + w1.w*h1.w;
        }
        float acc = a0 + a1;
        acc += __shfl_xor(acc, 1);
        acc += __shfl_xor(acc, 2);
        acc += __shfl_xor(acc, 4);
        acc += __shfl_xor(acc, 8);
        if (c == 0) acc += xg;        // gate sum complete at lanes 0,16,32,48

        // gather the 4 gates to ALL lanes (broadcast shfl), run cell redundantly
        float gi = __shfl(acc, 0);
        float gf = __shfl(acc, 16);
        float gg = __shfl(acc, 32);
        float go = __shfl(acc, 48);
        float i_ = 1.f / (1.f + __expf(-gi));
        float f_ = 1.f / (1.f + __expf(-gf));
        float eg = __expf(2.f * gg);
        float g_ = (eg - 1.f) / (eg + 1.f);
        float o_ = 1.f / (1.f + __expf(-go));
        cst = f_ * cst + i_ * g_;
        float ec = __expf(2.f * cst);
        float tc = (ec - 1.f) / (ec + 1.f);
        float h = o_ * tc;

        if (lane == 0) {
            unsigned long long pk = (unsigned long long)__float_as_uint(h)
                                  | ((unsigned long long)(unsigned)(s + 1) << 32);
            __hip_atomic_store(&myh[(s & 1) * 512 + j], pk,
                               __ATOMIC_RELAXED, __HIP_MEMORY_SCOPE_AGENT);
            out[(long)t * 1024 + dir * 512 + j] = h;   // off critical path
        }
    }
}

// ---------------------------------------------------------------------------
__global__ __launch_bounds__(128) void gather_emb(
    const int* __restrict__ en, const float* __restrict__ emb, float* __restrict__ x0)
{
    const int t = blockIdx.x;
    ((float4*)(x0 + (long)t * 512))[threadIdx.x] =
        ((const float4*)(emb + (long)en[t] * 512))[threadIdx.x];
}

__global__ __launch_bounds__(256) void add_h(
    const float* __restrict__ o2, float* __restrict__ h)
{
    const long i = (long)blockIdx.x * 256 + threadIdx.x;   // 1024*512
    const long t = i >> 9, j = i & 511;
    h[i] = o2[t * 1024 + j] + o2[t * 1024 + 512 + j];
}

__global__ __launch_bounds__(256) void zkl_kernel(
    const float* __restrict__ mu, const float* __restrict__ sp,
    const float* __restrict__ eps, float* __restrict__ z, float* __restrict__ klsum)
{
    __shared__ float w4[4];
    const int i = blockIdx.x * 256 + threadIdx.x;
    float m = mu[i], x = sp[i];
    float sg = (x > 20.f) ? x : log1pf(expf(x));   // softplus
    z[i] = m + eps[i] * sg;
    float kl = 0.5f * (sg * sg + m * m - 1.f) - logf(sg);
#pragma unroll
    for (int o = 1; o < 64; o <<= 1) kl += __shfl_xor(kl, o);
    if ((threadIdx.x & 63) == 0) w4[threadIdx.x >> 6] = kl;
    __syncthreads();
    if (threadIdx.x == 0) atomicAdd(klsum, w4[0] + w4[1] + w4[2] + w4[3]);
}

__global__ __launch_bounds__(64) void pos_kernel(
    const float* __restrict__ z, const float* __restrict__ E_en,
    const int* __restrict__ en, float* __restrict__ pos)
{
    const int t = blockIdx.x, lane = threadIdx.x;
    const float4* zr = (const float4*)(z + (long)t * 512);
    const float4* er = (const float4*)(E_en + (long)en[t] * 512);
    float s = 0.f;
#pragma unroll
    for (int q = 0; q < 2; ++q) {
        float4 a = zr[lane + q * 64], b = er[lane + q * 64];
        s += a.x * b.x + a.y * b.y + a.z * b.z + a.w * b.w;
    }
#pragma unroll
    for (int o = 1; o < 64; o <<= 1) s += __shfl_xor(s, o);
    if (lane == 0) pos[t] = expf(s);
}

__global__ __launch_bounds__(256) void finalize_kernel(
    const float* __restrict__ pos, const float* __restrict__ neg,
    const float* __restrict__ scal, float* __restrict__ out)
{
    __shared__ float w4[4];
    const int tid = threadIdx.x;
    float s = 0.f;
#pragma unroll
    for (int q = 0; q < 4; ++q) {
        int t = tid + q * 256;
        s += pos[t] / (pos[t] + neg[t]);
    }
#pragma unroll
    for (int o = 1; o < 64; o <<= 1) s += __shfl_xor(s, o);
    if ((tid & 63) == 0) w4[tid >> 6] = s;
    __syncthreads();
    if (tid == 0) {
        float sum_x = w4[0] + w4[1] + w4[2] + w4[3];
        // -(sum_x + sum_y - kl) ; sum_y = psum/1024
        out[0] = scal[0] - sum_x - scal[1] * (1.f / 1024.f);
    }
}

// ---------------------------------------------------------------------------
extern "C" void kernel_launch(void* const* d_in, const int* in_sizes, int n_in,
                              void* d_out, int out_size, void* d_ws, size_t ws_size,
                              hipStream_t stream)
{
    const int*   en     = (const int*)d_in[0];
    const int*   fr     = (const int*)d_in[1];
    const int*   en_neg = (const int*)d_in[2];
    const int*   fr_neg = (const int*)d_in[3];
    const float* emb    = (const float*)d_in[4];
    const float* Wih0   = (const float*)d_in[5];
    const float* Whh0   = (const float*)d_in[6];
    const float* b0     = (const float*)d_in[7];
    const float* Wih1   = (const float*)d_in[8];
    const float* Whh1   = (const float*)d_in[9];
    const float* b1     = (const float*)d_in[10];
    const float* Wih2   = (const float*)d_in[11];
    const float* Whh2   = (const float*)d_in[12];
    const float* b2     = (const float*)d_in[13];
    const float* Wmu1   = (const float*)d_in[14];
    const float* bmu1   = (const float*)d_in[15];
    const float* Wmu2   = (const float*)d_in[16];
    const float* bmu2   = (const float*)d_in[17];
    const float* Ws1    = (const float*)d_in[18];
    const float* bs1    = (const float*)d_in[19];
    const float* Ws2    = (const float*)d_in[20];
    const float* bs2    = (const float*)d_in[21];
    const float* E_en   = (const float*)d_in[22];
    const float* E_fr   = (const float*)d_in[23];
    const float* eps    = (const float*)d_in[24];
    float* out = (float*)d_out;

    float* w = (float*)d_ws;
    float* x0   = w;  w += 1024 * 512;
    float* bufA = w;  w += 1024 * 1024;
    float* bufB = w;  w += 1024 * 1024;
    float* Xf   = w;  w += 1024 * 2048;
    float* Xb   = w;  w += 1024 * 2048;
    float* h    = w;  w += 1024 * 512;
    float* tmp  = w;  w += 1024 * 512;
    float* mu   = w;  w += 1024 * 512;
    float* sp   = w;  w += 1024 * 512;
    float* z    = w;  w += 1024 * 512;
    float* pos  = w;  w += 1024;
    float* neg  = w;  w += 1024;
    float* negf = w;  w += 1024;                 // neg..negf contiguous
    unsigned long long* hbuf = (unsigned long long*)w; w += 4096;  // 2x2x512 slots x 8B
    float* scal = w;  w += 2;                    // [klsum, psum]

    // zero accumulators (ws is poisoned 0xAA before every launch)
    hipMemsetAsync(neg, 0, 2048 * sizeof(float), stream);
    hipMemsetAsync(scal, 0, 2 * sizeof(float), stream);

    gather_emb<<<1024, 128, 0, stream>>>(en, emb, x0);

    // ---- layer 0 (in = x0, K=512) -> bufA
    gemm_nt<false, false, 0><<<dim3(16, 32), 256, 0, stream>>>(
        x0, Wih0,               b0,        nullptr, Xf, nullptr, nullptr, 1024, 2048, 512);
    gemm_nt<false, false, 0><<<dim3(16, 32), 256, 0, stream>>>(
        x0, Wih0 + 2048 * 512,  b0 + 2048, nullptr, Xb, nullptr, nullptr, 1024, 2048, 512);
    hipMemsetAsync(hbuf, 0, 4096 * 8, stream);
    lstm_scan<<<256, 256, 0, stream>>>(Xf, Xb, Whh0, bufA, hbuf);

    // ---- layer 1 (in = bufA, K=1024) -> bufB
    gemm_nt<false, false, 0><<<dim3(16, 32), 256, 0, stream>>>(
        bufA, Wih1,               b1,        nullptr, Xf, nullptr, nullptr, 1024, 2048, 1024);
    gemm_nt<false, false, 0><<<dim3(16, 32), 256, 0, stream>>>(
        bufA, Wih1 + 2048 * 1024, b1 + 2048, nullptr, Xb, nullptr, nullptr, 1024, 2048, 1024);
    hipMemsetAsync(hbuf, 0, 4096 * 8, stream);
    lstm_scan<<<256, 256, 0, stream>>>(Xf, Xb, Whh1, bufB, hbuf);

    // ---- layer 2 (in = bufB, K=1024) -> bufA
    gemm_nt<false, false, 0><<<dim3(16, 32), 256, 0, stream>>>(
        bufB, Wih2,               b2,        nullptr, Xf, nullptr, nullptr, 1024, 2048, 1024);
    gemm_nt<false, false, 0><<<dim3(16, 32), 256, 0, stream>>>(
        bufB, Wih2 + 2048 * 1024, b2 + 2048, nullptr, Xb, nullptr, nullptr, 1024, 2048, 1024);
    hipMemsetAsync(hbuf, 0, 4096 * 8, stream);
    lstm_scan<<<256, 256, 0, stream>>>(Xf, Xb, Whh2, bufA, hbuf);

    // h = hf + hb
    add_h<<<2048, 256, 0, stream>>>(bufA, h);

    // inference nets
    gemm_nt<false, true, 0><<<dim3(16, 8), 256, 0, stream>>>(
        h,   Wmu1, bmu1, nullptr, tmp, nullptr, nullptr, 1024, 512, 512);
    gemm_nt<false, false, 0><<<dim3(16, 8), 256, 0, stream>>>(
        tmp, Wmu2, bmu2, nullptr, mu,  nullptr, nullptr, 1024, 512, 512);
    gemm_nt<false, true, 0><<<dim3(16, 8), 256, 0, stream>>>(
        h,   Ws1,  bs1,  nullptr, tmp, nullptr, nullptr, 1024, 512, 512);
    gemm_nt<false, false, 0><<<dim3(16, 8), 256, 0, stream>>>(
        tmp, Ws2,  bs2,  nullptr, sp,  nullptr, nullptr, 1024, 512, 512);

    // z, KL
    zkl_kernel<<<2048, 256, 0, stream>>>(mu, sp, eps, z, scal);

    // scores
    pos_kernel<<<1024, 64, 0, stream>>>(z, E_en, en, pos);
    gemm_nt<true, false, 1><<<dim3(16, 128), 256, 0, stream>>>(
        z, E_en, nullptr, en_neg, neg,  nullptr, nullptr, 1024, 8192, 512);
    gemm_nt<true, false, 1><<<dim3(16, 128), 256, 0, stream>>>(
        z, E_fr, nullptr, fr_neg, negf, nullptr, nullptr, 1024, 8192, 512);
    gemm_nt<true, false, 2><<<dim3(16, 16), 256, 0, stream>>>(
        z, E_fr, nullptr, fr,     nullptr, negf, scal + 1, 1024, 1024, 512);

    finalize_kernel<<<1, 256, 0, stream>>>(pos, neg, scal, out);
}

// Round 3
// 7211.815 us; speedup vs baseline: 1.3305x; 1.3305x over previous
//
#include <hip/hip_runtime.h>
#include <hip/hip_bf16.h>

// EmbedAlign: emb gather -> 3-layer BiLSTM (seq scan) -> mu/sigma nets ->
// reparam z -> KL + negative-sampling scores + alignment marginal -> scalar.
// All fp32. D=512, L=1024, NNEG=8192, V=32000.

// ---------------------------------------------------------------------------
// Generic fp32 NT GEMM: C[M,N] = A[M,K] . B[N,K]^T (+bias) with epilogues.
// GATHER: B row n comes from B[idx[n]].  EPI: 0=store(+bias,+relu),
// 1=atomicAdd rowsum(exp(C)) into C-vector, 2=atomicAdd sum(exp/(exp+negf)).
// Tiles 64x64, BK=16, 256 threads, 4x4 per thread.
// ---------------------------------------------------------------------------
template<bool GATHER, bool RELU, int EPI>
__global__ __launch_bounds__(256) void gemm_nt(
    const float* __restrict__ A, const float* __restrict__ B,
    const float* __restrict__ bias, const int* __restrict__ idx,
    float* __restrict__ C, const float* __restrict__ negf,
    float* __restrict__ outsum, int M, int N, int K)
{
    __shared__ float As[16][68];
    __shared__ float Bs[16][68];
    __shared__ float wsum[4];

    const int tid = threadIdx.x;
    const int bm = blockIdx.x, bn = blockIdx.y;
    const int tx = tid & 15, ty = tid >> 4;
    const int lr = tid >> 2;          // 0..63: tile row being loaded
    const int lk = (tid & 3) * 4;     // 0,4,8,12: k sub-offset

    const long arow = (long)bm * 64 + lr;
    const int  brow = bn * 64 + lr;
    const long bsrc = GATHER ? (long)idx[brow] : (long)brow;
    const float* Ap = A + arow * K + lk;
    const float* Bp = B + bsrc * K + lk;

    float acc[4][4] = {};

    for (int k0 = 0; k0 < K; k0 += 16) {
        float4 av = *(const float4*)(Ap + k0);
        float4 bv = *(const float4*)(Bp + k0);
        __syncthreads();
        As[lk + 0][lr] = av.x; As[lk + 1][lr] = av.y;
        As[lk + 2][lr] = av.z; As[lk + 3][lr] = av.w;
        Bs[lk + 0][lr] = bv.x; Bs[lk + 1][lr] = bv.y;
        Bs[lk + 2][lr] = bv.z; Bs[lk + 3][lr] = bv.w;
        __syncthreads();
#pragma unroll
        for (int k = 0; k < 16; ++k) {
            float4 a = *(const float4*)&As[k][ty * 4];
            float4 b = *(const float4*)&Bs[k][tx * 4];
            float ar[4] = {a.x, a.y, a.z, a.w};
            float br[4] = {b.x, b.y, b.z, b.w};
#pragma unroll
            for (int i = 0; i < 4; ++i)
#pragma unroll
                for (int j = 0; j < 4; ++j)
                    acc[i][j] += ar[i] * br[j];
        }
    }

    const int row0 = bm * 64 + ty * 4, col0 = bn * 64 + tx * 4;

    if (EPI == 0) {
#pragma unroll
        for (int i = 0; i < 4; ++i) {
            float4 v;
            float vv[4];
#pragma unroll
            for (int j = 0; j < 4; ++j) {
                float x = acc[i][j];
                if (bias) x += bias[col0 + j];
                if (RELU) x = x > 0.f ? x : 0.f;
                vv[j] = x;
            }
            v.x = vv[0]; v.y = vv[1]; v.z = vv[2]; v.w = vv[3];
            *(float4*)&C[(long)(row0 + i) * N + col0] = v;
        }
    } else if (EPI == 1) {
        // per-row sum of exp over this tile's 64 cols -> atomicAdd C[row]
#pragma unroll
        for (int i = 0; i < 4; ++i) {
            float s = expf(acc[i][0]) + expf(acc[i][1]) +
                      expf(acc[i][2]) + expf(acc[i][3]);
            s += __shfl_xor(s, 1); s += __shfl_xor(s, 2);
            s += __shfl_xor(s, 4); s += __shfl_xor(s, 8);
            if (tx == 0) atomicAdd(&C[row0 + i], s);
        }
    } else {
        float t = 0.f;
#pragma unroll
        for (int i = 0; i < 4; ++i) {
            float nf = negf[row0 + i];
#pragma unroll
            for (int j = 0; j < 4; ++j) {
                float e = expf(acc[i][j]);
                t += e / (e + nf);
            }
        }
#pragma unroll
        for (int o = 1; o < 64; o <<= 1) t += __shfl_xor(t, o);
        if ((tid & 63) == 0) wsum[tid >> 6] = t;
        __syncthreads();
        if (tid == 0) atomicAdd(outsum, wsum[0] + wsum[1] + wsum[2] + wsum[3]);
    }
}

// ---------------------------------------------------------------------------
// BiLSTM scan, 1024 steps. Grid = 256 WGs x 256 threads: blocks 0..127
// forward, 128..255 backward (1 WG/CU). Each WG owns 4 h-outputs (16 gate
// rows). This is the PROVEN baseline structure (7147.5us session): two
// barriers/step, ga[] handoff, wave-0 computes the 4 cells and publishes all
// 4 h-slots with ONE coalesced 4-lane store.
//
// R4 measurement (wave-per-h variant): scan 2047 -> 2862us. Counters showed
// VALUBusy 8.8%, bank-conflict 0, HBM 0.9% -> the scan is pure cross-WG
// rendezvous latency; intra-WG restructuring is irrelevant, but splitting
// the per-WG publish into 4 staggered single-lane stores (4x transactions,
// same-line partial writes, unsynced slowest-wave tail) cost +2400 cy/step.
// REVERTED. One retained change, motivated by the same mechanism:
//
//   hbuf slot padding: each WG's 4 slots now occupy a PRIVATE 128B-aligned
//   line (stride 16 u64/WG) instead of two WGs sharing each 64B line. The
//   per-step tag line is written by exactly one CU -> no cross-CU same-line
//   bounce on the rendezvous tail. Publish remains one 32B coalesced store.
//
// Whh chunk (16 rows x 512) staged ONCE into LDS, per-thread-contiguous
// stride-36 layout (conflict-free b128; measured SQ_LDS_BANK_CONFLICT = 0).
// The register allocator demoted register-resident weights two sessions
// running (VGPR 84 -> 52, per-step global reloads); LDS cannot be demoted.
// h staging buffer uses stride-36 chunks (also measured conflict-free).
//
// Cross-WG step exchange: each h published as 8-byte relaxed agent-scope
// atomic (low 32 = fp32 h, high 32 = tag s+1); readers poll slots directly.
// Buffers alternate by parity; tag s+1 on all slots implies every WG
// consumed h_{s-1}, so overwrite is safe.
// ---------------------------------------------------------------------------
__global__ __launch_bounds__(256, 1) void lstm_scan(
    const float* __restrict__ Xf, const float* __restrict__ Xb, // (1024,2048) pre-proj incl bias
    const float* __restrict__ Whh,                              // (2,2048,512)
    float* __restrict__ out,                                    // (1024,1024) [hf|hb]
    unsigned long long* __restrict__ hbuf)                      // (2 dirs,2 bufs,128 wg,16 u64), zeroed
{
    const int tid  = threadIdx.x;
    const int dir  = blockIdx.x >> 7;
    const int w    = blockIdx.x & 127;
    const int r    = tid >> 4;        // 0..15 gate-row within WG
    const int ck   = tid & 15;        // col chunk 0..15 (32 cols each)
    const int gate = r >> 2;
    const int jl   = r & 3;
    const int j    = w * 4 + jl;      // h index 0..511
    const int grow = gate * 512 + j;  // row in (2048 x 512) Whh

    __shared__ float Wl[256 * 36];    // per-thread 32 w + 4 pad
    __shared__ float hs[16 * 36];     // 16 chunks of 32 h + 4 pad
    __shared__ float ga[16];

    // ---- stage this WG's Whh chunk into LDS (once) ----
    {
        const float4* Wrow = (const float4*)(Whh + ((long)dir * 2048 + grow) * 512 + ck * 32);
        float4* wl4s = (float4*)Wl + tid * 9;
#pragma unroll
        for (int q = 0; q < 8; ++q) wl4s[q] = Wrow[q];
    }
    __syncthreads();

    const float* Xp = dir ? Xb : Xf;
    unsigned long long* myh = hbuf + dir * 4096;   // per dir: 2 bufs x 2048 u64

    // poll offsets for slots i=tid and i=tid+256 in the padded layout:
    // slot i -> u64 index (i>>2)*16 + (i&3)
    const int poff = (tid >> 2) * 16 + (tid & 3);  // second slot = poff + 1024

    float c = 0.f;
    bool dead = false;

    const float4* wl4 = (const float4*)Wl + tid * 9;
    const float4* hs4 = (const float4*)hs + ck * 9;

    for (int s = 0; s < 1024; ++s) {
        const int t = dir ? (1023 - s) : s;
        float xg = Xp[(long)t * 2048 + grow];   // prefetch, off critical path

        // ---- poll h_{s-1} slots (tag==s) ----
        unsigned long long* rb = myh + ((s + 1) & 1) * 2048;
        unsigned long long v0, v1;
        unsigned it = 0;
        for (;;) {
            v0 = __hip_atomic_load(&rb[poff],        __ATOMIC_RELAXED, __HIP_MEMORY_SCOPE_AGENT);
            v1 = __hip_atomic_load(&rb[poff + 1024], __ATOMIC_RELAXED, __HIP_MEMORY_SCOPE_AGENT);
            if (dead || ((int)(v0 >> 32) == s && (int)(v1 >> 32) == s)) break;
            if (++it > (1u << 20)) { dead = true; break; }   // anti-hang
        }
        // stage into padded chunks: slot i -> hs[(i>>5)*36 + (i&31)]
        hs[((tid) >> 5) * 36 + (tid & 31)]             = __uint_as_float((unsigned)v0);
        hs[((tid + 256) >> 5) * 36 + (tid & 31)]       = __uint_as_float((unsigned)v1);
        __syncthreads();

        // ---- 32-wide partial dot (8 float4 pairs), conflict-free LDS ----
        float a0 = 0.f, a1 = 0.f;
#pragma unroll
        for (int q = 0; q < 8; q += 2) {
            float4 w0 = wl4[q],     h0 = hs4[q];
            float4 w1 = wl4[q + 1], h1 = hs4[q + 1];
            a0 += w0.x*h0.x + w0.y*h0.y + w0.z*h0.z + w0.w*h0.w;
            a1 += w1.x*h1.x + w1.y*h1.y + w1.z*h1.z + w1.w*h1.w;
        }
        float acc = a0 + a1;
        acc += __shfl_xor(acc, 1);
        acc += __shfl_xor(acc, 2);
        acc += __shfl_xor(acc, 4);
        acc += __shfl_xor(acc, 8);
        if (ck == 0) ga[r] = acc + xg;
        __syncthreads();

        if (tid < 4) {
            float gi = ga[tid], gf = ga[4 + tid], gg = ga[8 + tid], go = ga[12 + tid];
            float i_ = 1.f / (1.f + __expf(-gi));
            float f_ = 1.f / (1.f + __expf(-gf));
            float eg = __expf(2.f * gg);
            float g_ = (eg - 1.f) / (eg + 1.f);
            float o_ = 1.f / (1.f + __expf(-go));
            c = f_ * c + i_ * g_;
            float ec = __expf(2.f * c);
            float tc = (ec - 1.f) / (ec + 1.f);
            float h = o_ * tc;
            unsigned long long pk = (unsigned long long)__float_as_uint(h)
                                  | ((unsigned long long)(unsigned)(s + 1) << 32);
            // ONE coalesced 4-lane 32B store into this WG's PRIVATE 128B line
            __hip_atomic_store(&myh[(s & 1) * 2048 + w * 16 + tid], pk,
                               __ATOMIC_RELAXED, __HIP_MEMORY_SCOPE_AGENT);
            out[(long)t * 1024 + dir * 512 + w * 4 + tid] = h;   // off critical path
        }
    }
}

// ---------------------------------------------------------------------------
__global__ __launch_bounds__(128) void gather_emb(
    const int* __restrict__ en, const float* __restrict__ emb, float* __restrict__ x0)
{
    const int t = blockIdx.x;
    ((float4*)(x0 + (long)t * 512))[threadIdx.x] =
        ((const float4*)(emb + (long)en[t] * 512))[threadIdx.x];
}

__global__ __launch_bounds__(256) void add_h(
    const float* __restrict__ o2, float* __restrict__ h)
{
    const long i = (long)blockIdx.x * 256 + threadIdx.x;   // 1024*512
    const long t = i >> 9, j = i & 511;
    h[i] = o2[t * 1024 + j] + o2[t * 1024 + 512 + j];
}

__global__ __launch_bounds__(256) void zkl_kernel(
    const float* __restrict__ mu, const float* __restrict__ sp,
    const float* __restrict__ eps, float* __restrict__ z, float* __restrict__ klsum)
{
    __shared__ float w4[4];
    const int i = blockIdx.x * 256 + threadIdx.x;
    float m = mu[i], x = sp[i];
    float sg = (x > 20.f) ? x : log1pf(expf(x));   // softplus
    z[i] = m + eps[i] * sg;
    float kl = 0.5f * (sg * sg + m * m - 1.f) - logf(sg);
#pragma unroll
    for (int o = 1; o < 64; o <<= 1) kl += __shfl_xor(kl, o);
    if ((threadIdx.x & 63) == 0) w4[threadIdx.x >> 6] = kl;
    __syncthreads();
    if (threadIdx.x == 0) atomicAdd(klsum, w4[0] + w4[1] + w4[2] + w4[3]);
}

__global__ __launch_bounds__(64) void pos_kernel(
    const float* __restrict__ z, const float* __restrict__ E_en,
    const int* __restrict__ en, float* __restrict__ pos)
{
    const int t = blockIdx.x, lane = threadIdx.x;
    const float4* zr = (const float4*)(z + (long)t * 512);
    const float4* er = (const float4*)(E_en + (long)en[t] * 512);
    float s = 0.f;
#pragma unroll
    for (int q = 0; q < 2; ++q) {
        float4 a = zr[lane + q * 64], b = er[lane + q * 64];
        s += a.x * b.x + a.y * b.y + a.z * b.z + a.w * b.w;
    }
#pragma unroll
    for (int o = 1; o < 64; o <<= 1) s += __shfl_xor(s, o);
    if (lane == 0) pos[t] = expf(s);
}

__global__ __launch_bounds__(256) void finalize_kernel(
    const float* __restrict__ pos, const float* __restrict__ neg,
    const float* __restrict__ scal, float* __restrict__ out)
{
    __shared__ float w4[4];
    const int tid = threadIdx.x;
    float s = 0.f;
#pragma unroll
    for (int q = 0; q < 4; ++q) {
        int t = tid + q * 256;
        s += pos[t] / (pos[t] + neg[t]);
    }
#pragma unroll
    for (int o = 1; o < 64; o <<= 1) s += __shfl_xor(s, o);
    if ((tid & 63) == 0) w4[tid >> 6] = s;
    __syncthreads();
    if (tid == 0) {
        float sum_x = w4[0] + w4[1] + w4[2] + w4[3];
        // -(sum_x + sum_y - kl) ; sum_y = psum/1024
        out[0] = scal[0] - sum_x - scal[1] * (1.f / 1024.f);
    }
}

// ---------------------------------------------------------------------------
extern "C" void kernel_launch(void* const* d_in, const int* in_sizes, int n_in,
                              void* d_out, int out_size, void* d_ws, size_t ws_size,
                              hipStream_t stream)
{
    const int*   en     = (const int*)d_in[0];
    const int*   fr     = (const int*)d_in[1];
    const int*   en_neg = (const int*)d_in[2];
    const int*   fr_neg = (const int*)d_in[3];
    const float* emb    = (const float*)d_in[4];
    const float* Wih0   = (const float*)d_in[5];
    const float* Whh0   = (const float*)d_in[6];
    const float* b0     = (const float*)d_in[7];
    const float* Wih1   = (const float*)d_in[8];
    const float* Whh1   = (const float*)d_in[9];
    const float* b1     = (const float*)d_in[10];
    const float* Wih2   = (const float*)d_in[11];
    const float* Whh2   = (const float*)d_in[12];
    const float* b2     = (const float*)d_in[13];
    const float* Wmu1   = (const float*)d_in[14];
    const float* bmu1   = (const float*)d_in[15];
    const float* Wmu2   = (const float*)d_in[16];
    const float* bmu2   = (const float*)d_in[17];
    const float* Ws1    = (const float*)d_in[18];
    const float* bs1    = (const float*)d_in[19];
    const float* Ws2    = (const float*)d_in[20];
    const float* bs2    = (const float*)d_in[21];
    const float* E_en   = (const float*)d_in[22];
    const float* E_fr   = (const float*)d_in[23];
    const float* eps    = (const float*)d_in[24];
    float* out = (float*)d_out;

    float* w = (float*)d_ws;
    float* x0   = w;  w += 1024 * 512;
    float* bufA = w;  w += 1024 * 1024;
    float* bufB = w;  w += 1024 * 1024;
    float* Xf   = w;  w += 1024 * 2048;
    float* Xb   = w;  w += 1024 * 2048;
    float* h    = w;  w += 1024 * 512;
    float* tmp  = w;  w += 1024 * 512;
    float* mu   = w;  w += 1024 * 512;
    float* sp   = w;  w += 1024 * 512;
    float* z    = w;  w += 1024 * 512;
    float* pos  = w;  w += 1024;
    float* neg  = w;  w += 1024;
    float* negf = w;  w += 1024;                 // neg..negf contiguous
    unsigned long long* hbuf = (unsigned long long*)w; w += 16384; // 2x2x128x16 u64 = 64KB
    float* scal = w;  w += 2;                    // [klsum, psum]

    // zero accumulators (ws is poisoned 0xAA before every launch)
    hipMemsetAsync(neg, 0, 2048 * sizeof(float), stream);
    hipMemsetAsync(scal, 0, 2 * sizeof(float), stream);

    gather_emb<<<1024, 128, 0, stream>>>(en, emb, x0);

    // ---- layer 0 (in = x0, K=512) -> bufA
    gemm_nt<false, false, 0><<<dim3(16, 32), 256, 0, stream>>>(
        x0, Wih0,               b0,        nullptr, Xf, nullptr, nullptr, 1024, 2048, 512);
    gemm_nt<false, false, 0><<<dim3(16, 32), 256, 0, stream>>>(
        x0, Wih0 + 2048 * 512,  b0 + 2048, nullptr, Xb, nullptr, nullptr, 1024, 2048, 512);
    hipMemsetAsync(hbuf, 0, 8192 * 8, stream);
    lstm_scan<<<256, 256, 0, stream>>>(Xf, Xb, Whh0, bufA, hbuf);

    // ---- layer 1 (in = bufA, K=1024) -> bufB
    gemm_nt<false, false, 0><<<dim3(16, 32), 256, 0, stream>>>(
        bufA, Wih1,               b1,        nullptr, Xf, nullptr, nullptr, 1024, 2048, 1024);
    gemm_nt<false, false, 0><<<dim3(16, 32), 256, 0, stream>>>(
        bufA, Wih1 + 2048 * 1024, b1 + 2048, nullptr, Xb, nullptr, nullptr, 1024, 2048, 1024);
    hipMemsetAsync(hbuf, 0, 8192 * 8, stream);
    lstm_scan<<<256, 256, 0, stream>>>(Xf, Xb, Whh1, bufB, hbuf);

    // ---- layer 2 (in = bufB, K=1024) -> bufA
    gemm_nt<false, false, 0><<<dim3(16, 32), 256, 0, stream>>>(
        bufB, Wih2,               b2,        nullptr, Xf, nullptr, nullptr, 1024, 2048, 1024);
    gemm_nt<false, false, 0><<<dim3(16, 32), 256, 0, stream>>>(
        bufB, Wih2 + 2048 * 1024, b2 + 2048, nullptr, Xb, nullptr, nullptr, 1024, 2048, 1024);
    hipMemsetAsync(hbuf, 0, 8192 * 8, stream);
    lstm_scan<<<256, 256, 0, stream>>>(Xf, Xb, Whh2, bufA, hbuf);

    // h = hf + hb
    add_h<<<2048, 256, 0, stream>>>(bufA, h);

    // inference nets
    gemm_nt<false, true, 0><<<dim3(16, 8), 256, 0, stream>>>(
        h,   Wmu1, bmu1, nullptr, tmp, nullptr, nullptr, 1024, 512, 512);
    gemm_nt<false, false, 0><<<dim3(16, 8), 256, 0, stream>>>(
        tmp, Wmu2, bmu2, nullptr, mu,  nullptr, nullptr, 1024, 512, 512);
    gemm_nt<false, true, 0><<<dim3(16, 8), 256, 0, stream>>>(
        h,   Ws1,  bs1,  nullptr, tmp, nullptr, nullptr, 1024, 512, 512);
    gemm_nt<false, false, 0><<<dim3(16, 8), 256, 0, stream>>>(
        tmp, Ws2,  bs2,  nullptr, sp,  nullptr, nullptr, 1024, 512, 512);

    // z, KL
    zkl_kernel<<<2048, 256, 0, stream>>>(mu, sp, eps, z, scal);

    // scores
    pos_kernel<<<1024, 64, 0, stream>>>(z, E_en, en, pos);
    gemm_nt<true, false, 1><<<dim3(16, 128), 256, 0, stream>>>(
        z, E_en, nullptr, en_neg, neg,  nullptr, nullptr, 1024, 8192, 512);
    gemm_nt<true, false, 1><<<dim3(16, 128), 256, 0, stream>>>(
        z, E_fr, nullptr, fr_neg, negf, nullptr, nullptr, 1024, 8192, 512);
    gemm_nt<true, false, 2><<<dim3(16, 16), 256, 0, stream>>>(
        z, E_fr, nullptr, fr,     nullptr, negf, scal + 1, 1024, 1024, 512);

    finalize_kernel<<<1, 256, 0, stream>>>(pos, neg, scal, out);
}